// Round 4
// baseline (219.282 us; speedup 1.0000x reference)
//
#include <hip/hip_runtime.h>
#include <math.h>

#define DM   1024
#define DS   64
#define BATCH 8
#define SEQ  2048
#define CL   32          // chunk length
#define NC   64          // number of chunks (SEQ/CL)

typedef __bf16 bf16x8 __attribute__((ext_vector_type(8)));
typedef float  f32x4  __attribute__((ext_vector_type(4)));

// ---------------------------------------------------------------------------
// Kernel W: pre-convert W_delta|W_Bp|W_Cp into packed bf16, K-tiled:
// Wp[(kt*192 + n)*32 + kk], k = kt*32+kk.  With this layout a wave's B-frag
// load for one (kt, n-tile) is a single contiguous 1 KB segment.
// ---------------------------------------------------------------------------
__global__ __launch_bounds__(256) void wconv_kernel(
    const float* __restrict__ Wd, const float* __restrict__ Wb,
    const float* __restrict__ Wc, __bf16* __restrict__ Wp)
{
    int idx = blockIdx.x * 256 + threadIdx.x;   // n*1024 + k
    int k  = idx & 1023;
    int n  = idx >> 10;                          // 0..191
    const float* W = (n < 64) ? Wd : (n < 128 ? Wb : Wc);
    float v = W[(size_t)(n & 63) * DM + k];
    int kt = k >> 5, kk = k & 31;
    Wp[((size_t)kt * 192 + n) * 32 + kk] = (__bf16)v;
}

// ---------------------------------------------------------------------------
// Kernel A: barrier-free streaming MFMA projection.
// C[16384 x 192] = x @ Wp^T.  No LDS staging, no K-loop barriers: A and B
// fragments are loaded DIRECTLY from global into registers in MFMA fragment
// order (A: 16 rows x 128 B per load inst; B: one contiguous 1 KB segment
// per frag load).  Register ping-pong prefetch (kt+1 issued before MFMA(kt)).
// Block: 256 thr = 4 waves = (m-strip w_m, K-half w_k).  Wave computes
// 16M x 192N over K/2; K-halves combined once through LDS at the end.
// Grid 512 -> 2 blocks/CU -> 8 waves/CU (2/SIMD) for latency hiding.
// ---------------------------------------------------------------------------
__global__ __launch_bounds__(256) void proj_mfma(
    const float* __restrict__ x, const __bf16* __restrict__ Wp,
    const float* __restrict__ bd, const float* __restrict__ bb,
    const float* __restrict__ bc,
    float* __restrict__ delta_g, float* __restrict__ u_g,
    float* __restrict__ ct_g)
{
    __shared__ float sAcc[2][64][48];            // 24 KB, used once at end

    const int tid  = threadIdx.x;
    const int wv   = tid >> 6;
    const int lane = tid & 63;
    const int l15  = lane & 15, quad = lane >> 4;
    const int w_m  = wv & 1;                     // m-strip within block
    const int w_k  = wv >> 1;                    // K-half
    const int row0 = blockIdx.x * 32 + w_m * 16;

    const float*  xg = x + (size_t)(row0 + l15) * DM + quad * 8;
    const __bf16* wg = Wp + (size_t)l15 * 32 + quad * 8;

    f32x4 acc[12];
    #pragma unroll
    for (int i = 0; i < 12; ++i) acc[i] = (f32x4){0.f, 0.f, 0.f, 0.f};

    float4 aA0, aA1, aB0, aB1;
    uint4  bA[12], bB[12];

    #define LOADA(s0, s1, kt) do {                                            \
        s0 = *(const float4*)(xg + (kt) * 32);                                \
        s1 = *(const float4*)(xg + (kt) * 32 + 4);                            \
    } while (0)
    #define LOADB(dst, kt) do {                                               \
        const __bf16* p = wg + (size_t)(kt) * (192 * 32);                     \
        _Pragma("unroll")                                                     \
        for (int nt = 0; nt < 12; ++nt)                                       \
            dst[nt] = *(const uint4*)(p + (size_t)nt * (16 * 32));            \
    } while (0)
    #define COMPUTE(s0, s1, bsrc) do {                                        \
        bf16x8 av = {(__bf16)s0.x, (__bf16)s0.y, (__bf16)s0.z, (__bf16)s0.w,  \
                     (__bf16)s1.x, (__bf16)s1.y, (__bf16)s1.z, (__bf16)s1.w}; \
        _Pragma("unroll")                                                     \
        for (int nt = 0; nt < 12; ++nt)                                       \
            acc[nt] = __builtin_amdgcn_mfma_f32_16x16x32_bf16(                \
                av, __builtin_bit_cast(bf16x8, bsrc[nt]), acc[nt], 0, 0, 0);  \
    } while (0)

    const int kt0 = w_k * 16;                    // this wave's K-half
    LOADA(aA0, aA1, kt0);
    LOADB(bA, kt0);

    #pragma unroll
    for (int k2 = 0; k2 < 8; ++k2) {
        const int kt = kt0 + k2 * 2;
        LOADB(bB, kt + 1);                       // prefetch odd tile
        LOADA(aB0, aB1, kt + 1);
        COMPUTE(aA0, aA1, bA);                   // even tile
        if (k2 < 7) {
            LOADA(aA0, aA1, kt + 2);             // prefetch next even tile
            LOADB(bA, kt + 2);
        }
        COMPUTE(aB0, aB1, bB);                   // odd tile
    }
    #undef LOADA
    #undef LOADB
    #undef COMPUTE

    // combine K-halves (one barrier in the whole kernel)
    if (w_k == 1) {
        #pragma unroll
        for (int nt = 0; nt < 12; ++nt)
            *(f32x4*)&sAcc[w_m][lane][nt * 4] = acc[nt];
    }
    __syncthreads();
    if (w_k == 0) {
        #pragma unroll
        for (int nt = 0; nt < 12; ++nt) {
            f32x4 o = *(const f32x4*)&sAcc[w_m][lane][nt * 4];
            acc[nt] += o;
        }
        // epilogue: bias + activations + stores
        #pragma unroll
        for (int nt = 0; nt < 12; ++nt) {
            int mat = nt >> 2;                   // 0:delta 1:u 2:ct
            int col = ((nt & 3) << 4) + l15;     // 0..63
            float bias = (mat == 0) ? bd[col] : (mat == 1 ? bb[col] : bc[col]);
            #pragma unroll
            for (int r = 0; r < 4; ++r) {
                int m = row0 + quad * 4 + r;
                float v = acc[nt][r] + bias;
                if (mat == 0) {
                    float sp = (v > 20.f) ? v : log1pf(__expf(v));
                    delta_g[(size_t)m * DS + col] = sp;
                } else if (mat == 1) {
                    u_g[(size_t)m * DS + col] = v * x[(size_t)m * DM + col];
                } else {
                    ct_g[(size_t)m * DS + col] = v;
                }
            }
        }
    }
}

// ---------------------------------------------------------------------------
// Kernel B (pass 1): per-chunk local recurrence from h=0.
// A_log pre-scaled by log2(e) at fragment load -> exp2f (1 VALU op fewer
// per element than expf's internal scale).
// ---------------------------------------------------------------------------
__global__ __launch_bounds__(256) void pass1_kernel(
    const float* __restrict__ delta_g, const float* __restrict__ u_g,
    const float* __restrict__ A_log,
    float* __restrict__ E, float* __restrict__ Dsum)
{
    __shared__ float s_d[CL * 64];
    __shared__ float s_u[CL * 64];
    const int c = blockIdx.x, b = blockIdx.y, tid = threadIdx.x;
    const int t0 = c * CL;

    const float4* dg = (const float4*)(delta_g + ((size_t)b * SEQ + t0) * DS);
    const float4* ug = (const float4*)(u_g     + ((size_t)b * SEQ + t0) * DS);
    #pragma unroll
    for (int it = 0; it < (CL * 64 / 4) / 256; ++it) {
        int f = tid + it * 256;
        ((float4*)s_d)[f] = dg[f];
        ((float4*)s_u)[f] = ug[f];
    }

    const int i  = tid & 63;
    const int jg = tid >> 6;
    float alog[16];
    {
        const float4* ar = (const float4*)(A_log + i * 64 + jg * 16);
        #pragma unroll
        for (int q = 0; q < 4; ++q) {
            float4 v = ar[q];
            alog[4*q+0] = v.x * 1.44269504f; alog[4*q+1] = v.y * 1.44269504f;
            alog[4*q+2] = v.z * 1.44269504f; alog[4*q+3] = v.w * 1.44269504f;
        }
    }
    __syncthreads();

    float h[16];
    #pragma unroll
    for (int k = 0; k < 16; ++k) h[k] = 0.f;
    float dsum = 0.f;

    for (int t = 0; t < CL; ++t) {
        float d = s_d[t * 64 + i];
        dsum += d;
        const float* up = s_u + t * 64 + jg * 16;
        #pragma unroll
        for (int k = 0; k < 16; ++k)
            h[k] = exp2f(alog[k] * d) * h[k] + up[k];
    }

    float* eo = E + (((size_t)c * BATCH + b) * 64 + i) * 64 + jg * 16;
    #pragma unroll
    for (int q = 0; q < 4; ++q)
        ((float4*)eo)[q] = make_float4(h[4*q], h[4*q+1], h[4*q+2], h[4*q+3]);
    if (jg == 0) Dsum[((size_t)c * BATCH + b) * 64 + i] = dsum;
}

// ---------------------------------------------------------------------------
// Kernel C (pass 2): sequential chunk scan, parallel over B*64*64 elements.
// 64-thread blocks x 512 -> 2 blocks/CU on all 256 CUs (was 128 blocks).
// Decay exp2 off the carry chain; E/Dsum prefetched 4 iterations ahead.
// ---------------------------------------------------------------------------
__global__ __launch_bounds__(64) void pass2_kernel(
    const float* __restrict__ A_log, const float* __restrict__ E,
    const float* __restrict__ Dsum, float* __restrict__ Sin)
{
    const int g = blockIdx.x * 64 + threadIdx.x;      // 0..32767
    const int b = g >> 12;
    const int e = g & 4095;
    const int i = e >> 6;
    const float al = A_log[e] * 1.44269504f;

    float Eb[4], db[4];
    #pragma unroll
    for (int p = 0; p < 4; ++p) {
        size_t nb = (size_t)p * BATCH + b;
        Eb[p] = E[nb * 4096 + e];
        db[p] = exp2f(al * Dsum[nb * 64 + i]);
    }

    float carry = 0.f;
    #pragma unroll 4
    for (int c = 0; c < NC; ++c) {
        const int s = c & 3;
        float Ec = Eb[s], dc = db[s];
        if (c + 4 < NC) {
            size_t nb = (size_t)(c + 4) * BATCH + b;
            Eb[s] = E[nb * 4096 + e];
            db[s] = exp2f(al * Dsum[nb * 64 + i]);
        }
        Sin[((size_t)c * BATCH + b) * 4096 + e] = carry;
        carry = dc * carry + Ec;                      // the only serial dep
    }
}

// ---------------------------------------------------------------------------
// Kernel D (pass 3): replay chunk from true incoming state, emit
//   y[b,t,i] = sum_j Ct[b,t,j] * h[b,i,j]
// Thread -> (i = tid>>2, jg = tid&3): 4 j-partials per i in adjacent lanes
// -> 2x shfl_xor, no in-loop barriers.
// ---------------------------------------------------------------------------
__global__ __launch_bounds__(256) void pass3_kernel(
    const float* __restrict__ delta_g, const float* __restrict__ u_g,
    const float* __restrict__ ct_g, const float* __restrict__ A_log,
    const float* __restrict__ Sin, float* __restrict__ out)
{
    __shared__ float s_d[CL * 64];
    __shared__ float s_u[CL * 64];
    __shared__ float s_c[CL * 64];

    const int c = blockIdx.x, b = blockIdx.y, tid = threadIdx.x;
    const int t0 = c * CL;

    const float4* dg = (const float4*)(delta_g + ((size_t)b * SEQ + t0) * DS);
    const float4* ug = (const float4*)(u_g     + ((size_t)b * SEQ + t0) * DS);
    const float4* cg = (const float4*)(ct_g    + ((size_t)b * SEQ + t0) * DS);
    #pragma unroll
    for (int it = 0; it < (CL * 64 / 4) / 256; ++it) {
        int f = tid + it * 256;
        ((float4*)s_d)[f] = dg[f];
        ((float4*)s_u)[f] = ug[f];
        ((float4*)s_c)[f] = cg[f];
    }

    const int i  = tid >> 2;                          // 0..63
    const int jg = tid & 3;                           // 0..3

    float alog[16];
    {
        const float4* ar = (const float4*)(A_log + i * 64 + jg * 16);
        #pragma unroll
        for (int q = 0; q < 4; ++q) {
            float4 v = ar[q];
            alog[4*q+0] = v.x * 1.44269504f; alog[4*q+1] = v.y * 1.44269504f;
            alog[4*q+2] = v.z * 1.44269504f; alog[4*q+3] = v.w * 1.44269504f;
        }
    }

    float h[16];
    {
        const float4* hin = (const float4*)(
            Sin + (((size_t)c * BATCH + b) * 64 + i) * 64 + jg * 16);
        #pragma unroll
        for (int q = 0; q < 4; ++q) {
            float4 v = hin[q];
            h[4*q+0] = v.x; h[4*q+1] = v.y; h[4*q+2] = v.z; h[4*q+3] = v.w;
        }
    }
    __syncthreads();

    for (int t = 0; t < CL; ++t) {
        float d = s_d[t * 64 + i];
        const float* up = s_u + t * 64 + jg * 16;
        const float* cp = s_c + t * 64 + jg * 16;
        float part = 0.f;
        #pragma unroll
        for (int k = 0; k < 16; ++k) {
            h[k] = exp2f(alog[k] * d) * h[k] + up[k];
            part += cp[k] * h[k];
        }
        part += __shfl_xor(part, 1);
        part += __shfl_xor(part, 2);
        if (jg == 0)
            out[((size_t)b * SEQ + t0 + t) * DS + i] = part;
    }
}

// ---------------------------------------------------------------------------
// Inputs: 0:x 1..6:(cog/beh/env dead) 7:W_delta 8:b_delta 9:W_Bp 10:b_Bp
//         11:W_Cp 12:b_Cp 13:A_log
// ---------------------------------------------------------------------------
extern "C" void kernel_launch(void* const* d_in, const int* in_sizes, int n_in,
                              void* d_out, int out_size, void* d_ws, size_t ws_size,
                              hipStream_t stream)
{
    const float* x     = (const float*)d_in[0];
    const float* Wd    = (const float*)d_in[7];
    const float* bd    = (const float*)d_in[8];
    const float* Wb    = (const float*)d_in[9];
    const float* bb    = (const float*)d_in[10];
    const float* Wc    = (const float*)d_in[11];
    const float* bc    = (const float*)d_in[12];
    const float* A_log = (const float*)d_in[13];
    float* out = (float*)d_out;

    float* ws = (float*)d_ws;
    float* delta_g = ws;                       // 1,048,576 floats
    float* u_g     = ws + 1 * 1048576;         // 1,048,576
    float* ct_g    = ws + 2 * 1048576;         // 1,048,576
    float* E       = ws + 3 * 1048576;         // 2,097,152
    float* Sin     = ws + 5 * 1048576;         // 2,097,152
    float* Dsum    = ws + 7 * 1048576;         // 32,768
    __bf16* Wp     = (__bf16*)E;               // aliases E (dead by pass1)

    wconv_kernel<<<768, 256, 0, stream>>>(Wd, Wb, Wc, Wp);
    proj_mfma<<<512, 256, 0, stream>>>(
        x, Wp, bd, bb, bc, delta_g, u_g, ct_g);
    pass1_kernel<<<dim3(NC, BATCH), 256, 0, stream>>>(
        delta_g, u_g, A_log, E, Dsum);
    pass2_kernel<<<512, 64, 0, stream>>>(
        A_log, E, Dsum, Sin);
    pass3_kernel<<<dim3(NC, BATCH), 256, 0, stream>>>(
        delta_g, u_g, ct_g, A_log, Sin, out);
}

// Round 6
// 199.490 us; speedup vs baseline: 1.0992x; 1.0992x over previous
//
#include <hip/hip_runtime.h>
#include <math.h>

#define DM   1024
#define DS   64
#define BATCH 8
#define SEQ  2048
#define CL   32          // chunk length
#define NC   64          // number of chunks (SEQ/CL)

typedef __bf16 bf16x8 __attribute__((ext_vector_type(8)));
typedef float  f32x4  __attribute__((ext_vector_type(4)));
typedef float  f32x16 __attribute__((ext_vector_type(16)));

// Bare v_exp_f32 (arg already in log2 domain). exp2f/expf libcalls have
// range-handling overhead.
#if __has_builtin(__builtin_amdgcn_exp2f)
#define EXP2(v) __builtin_amdgcn_exp2f(v)
#else
#define EXP2(v) __expf(0.69314718056f * (v))
#endif

// ---------------------------------------------------------------------------
// Kernel W: pre-convert W_delta|W_Bp|W_Cp into packed bf16, K-tiled:
// Wp[(kt*192 + n)*32 + kk], k = kt*32+kk (kt = 32-wide K slab).
// ---------------------------------------------------------------------------
__global__ __launch_bounds__(256) void wconv_kernel(
    const float* __restrict__ Wd, const float* __restrict__ Wb,
    const float* __restrict__ Wc, __bf16* __restrict__ Wp)
{
    int idx = blockIdx.x * 256 + threadIdx.x;   // n*1024 + k
    int k  = idx & 1023;
    int n  = idx >> 10;                          // 0..191
    const float* W = (n < 64) ? Wd : (n < 128 ? Wb : Wc);
    float v = W[(size_t)(n & 63) * DM + k];
    int kt = k >> 5, kk = k & 31;
    Wp[((size_t)kt * 192 + n) * 32 + kk] = (__bf16)v;
}

// ---------------------------------------------------------------------------
// Kernel A: MFMA projection, v6 (v5 + staging-decomposition fix).
// B through double-buffered LDS, A in registers.  Block = 64M x 192N,
// 4 waves of 32M x 96N on 32x32x16 MFMA.  K-block 64, one barrier each.
// r5 BUG FIX: a 64-K slab = 2 ktl-slabs x 768 chunks (192 rows x 4 x 16B);
// chunk id g = ktl*768 + n*4 + c4 (ktl = it>=3 at compile time) -- the old
// g>>9/g&511 split left rows 128..191 of slab 0 UNSTAGED (NaN from
// uninitialized LDS).
// __launch_bounds__(256,1): grid 256 = 1 block/CU, so allow the full
// register budget -- protects the A ping-pong + B transit regs (~170 VGPR)
// from the r4-style allocator clamp.
// C layout (m74/m101): col=lane&31, row=(reg&3)+8*(reg>>2)+4*(lane>>5).
// ---------------------------------------------------------------------------
__global__ __launch_bounds__(256, 1) void proj_mfma(
    const float* __restrict__ x, const __bf16* __restrict__ Wp,
    const float* __restrict__ bd, const float* __restrict__ bb,
    const float* __restrict__ bc,
    float* __restrict__ delta_g, float* __restrict__ u_g,
    float* __restrict__ ct_g)
{
    __shared__ __bf16 sB[2][192 * 72];           // 54 KB total

    const int tid  = threadIdx.x;
    const int row0 = blockIdx.x * 64;

    const int lane = tid & 63, wv = tid >> 6;
    const int l31  = lane & 31, q = lane >> 5;   // q in {0,1}
    const int mbase = row0 + (wv & 1) * 32;
    const int nhalf = (wv >> 1) * 96;

    const float* xrow = x + (size_t)(mbase + l31) * DM;

    f32x16 acc[3];
    #pragma unroll
    for (int i = 0; i < 3; ++i)
        acc[i] = (f32x16){0,0,0,0,0,0,0,0,0,0,0,0,0,0,0,0};

    float4 aC[8], aN[8];
    uint4  wreg[6];

    // chunk g = tid + it*256 in [0,1536): ktl = g/768 (= it>=3, compile-time),
    // r = g - 768*ktl, n = r>>2, c4 = r&3.  Source is contiguous 16B chunks.
    #define LOADB(kb) do {                                                    \
        _Pragma("unroll")                                                     \
        for (int it = 0; it < 6; ++it) {                                      \
            int g   = tid + it * 256;                                         \
            int ktl = (it >= 3) ? 1 : 0;                                      \
            int r   = g - ktl * 768;                                          \
            int n   = r >> 2, c4 = r & 3;                                     \
            wreg[it] = *(const uint4*)(                                       \
                Wp + ((size_t)((kb) * 2 + ktl) * 192 + n) * 32 + c4 * 8);     \
        }                                                                     \
    } while (0)
    #define STAGEB(bi) do {                                                   \
        _Pragma("unroll")                                                     \
        for (int it = 0; it < 6; ++it) {                                      \
            int g   = tid + it * 256;                                         \
            int ktl = (it >= 3) ? 1 : 0;                                      \
            int r   = g - ktl * 768;                                          \
            int n   = r >> 2, c4 = r & 3;                                     \
            *(uint4*)&sB[bi][n * 72 + ktl * 32 + c4 * 8] = wreg[it];          \
        }                                                                     \
    } while (0)
    #define LOADA(dst, kb) do {                                               \
        _Pragma("unroll")                                                     \
        for (int s = 0; s < 4; ++s) {                                         \
            dst[2*s]   = *(const float4*)(xrow + (kb)*64 + s*16 + q*8);       \
            dst[2*s+1] = *(const float4*)(xrow + (kb)*64 + s*16 + q*8 + 4);   \
        }                                                                     \
    } while (0)
    #define COMPUTE(bi) do {                                                  \
        _Pragma("unroll")                                                     \
        for (int s = 0; s < 4; ++s) {                                         \
            float4 a0 = aC[2*s], a1 = aC[2*s+1];                              \
            bf16x8 av = {(__bf16)a0.x, (__bf16)a0.y, (__bf16)a0.z,            \
                         (__bf16)a0.w, (__bf16)a1.x, (__bf16)a1.y,            \
                         (__bf16)a1.z, (__bf16)a1.w};                         \
            _Pragma("unroll")                                                 \
            for (int nt = 0; nt < 3; ++nt) {                                  \
                bf16x8 bv = *(const bf16x8*)                                  \
                    &sB[bi][(nhalf + nt*32 + l31) * 72 + s*16 + q*8];         \
                acc[nt] = __builtin_amdgcn_mfma_f32_32x32x16_bf16(            \
                    av, bv, acc[nt], 0, 0, 0);                                \
            }                                                                 \
        }                                                                     \
    } while (0)

    // prologue
    LOADB(0);
    STAGEB(0);
    LOADA(aC, 0);
    __syncthreads();

    int buf = 0;
    for (int kb = 0; kb < 16; ++kb) {
        if (kb < 15) {
            LOADB(kb + 1);                       // global B for next block
            LOADA(aN, kb + 1);                   // global A for next block
        }
        COMPUTE(buf);                            // MFMA + ds_read on current
        if (kb < 15) STAGEB(buf ^ 1);            // write other buffer
        __syncthreads();                         // one barrier per k-block
        if (kb < 15) {
            #pragma unroll
            for (int i = 0; i < 8; ++i) aC[i] = aN[i];
        }
        buf ^= 1;
    }
    #undef LOADB
    #undef STAGEB
    #undef LOADA
    #undef COMPUTE

    // epilogue: bias + activations + stores
    #pragma unroll
    for (int nt = 0; nt < 3; ++nt) {
        int gn  = nhalf + nt * 32 + l31;         // 0..191
        int mat = (nhalf + nt * 32) >> 6;        // uniform per (wave,nt)
        int col = gn & 63;
        float bias = (mat == 0) ? bd[col] : (mat == 1 ? bb[col] : bc[col]);
        #pragma unroll
        for (int r = 0; r < 16; ++r) {
            int m = mbase + (r & 3) + 8 * (r >> 2) + 4 * q;
            float v = acc[nt][r] + bias;
            if (mat == 0) {
                float sp = (v > 20.f) ? v : __logf(1.f + __expf(v));
                delta_g[(size_t)m * DS + col] = sp;
            } else if (mat == 1) {
                u_g[(size_t)m * DS + col] = v * x[(size_t)m * DM + col];
            } else {
                ct_g[(size_t)m * DS + col] = v;
            }
        }
    }
}

// ---------------------------------------------------------------------------
// Kernel B (pass 1): per-chunk local recurrence from h=0. A_log prescaled
// by log2(e); EXP2 = bare v_exp_f32.
// ---------------------------------------------------------------------------
__global__ __launch_bounds__(256) void pass1_kernel(
    const float* __restrict__ delta_g, const float* __restrict__ u_g,
    const float* __restrict__ A_log,
    float* __restrict__ E, float* __restrict__ Dsum)
{
    __shared__ float s_d[CL * 64];
    __shared__ float s_u[CL * 64];
    const int c = blockIdx.x, b = blockIdx.y, tid = threadIdx.x;
    const int t0 = c * CL;

    const float4* dg = (const float4*)(delta_g + ((size_t)b * SEQ + t0) * DS);
    const float4* ug = (const float4*)(u_g     + ((size_t)b * SEQ + t0) * DS);
    #pragma unroll
    for (int it = 0; it < (CL * 64 / 4) / 256; ++it) {
        int f = tid + it * 256;
        ((float4*)s_d)[f] = dg[f];
        ((float4*)s_u)[f] = ug[f];
    }

    const int i  = tid & 63;
    const int jg = tid >> 6;
    float alog[16];
    {
        const float4* ar = (const float4*)(A_log + i * 64 + jg * 16);
        #pragma unroll
        for (int qq = 0; qq < 4; ++qq) {
            float4 v = ar[qq];
            alog[4*qq+0] = v.x * 1.44269504f; alog[4*qq+1] = v.y * 1.44269504f;
            alog[4*qq+2] = v.z * 1.44269504f; alog[4*qq+3] = v.w * 1.44269504f;
        }
    }
    __syncthreads();

    float h[16];
    #pragma unroll
    for (int k = 0; k < 16; ++k) h[k] = 0.f;
    float dsum = 0.f;

    for (int t = 0; t < CL; ++t) {
        float d = s_d[t * 64 + i];
        dsum += d;
        const float* up = s_u + t * 64 + jg * 16;
        #pragma unroll
        for (int k = 0; k < 16; ++k)
            h[k] = EXP2(alog[k] * d) * h[k] + up[k];
    }

    float* eo = E + (((size_t)c * BATCH + b) * 64 + i) * 64 + jg * 16;
    #pragma unroll
    for (int qq = 0; qq < 4; ++qq)
        ((float4*)eo)[qq] = make_float4(h[4*qq], h[4*qq+1], h[4*qq+2], h[4*qq+3]);
    if (jg == 0) Dsum[((size_t)c * BATCH + b) * 64 + i] = dsum;
}

// ---------------------------------------------------------------------------
// Kernel C (pass 2): sequential chunk scan, parallel over B*64*64 elements.
// Decay exp2 off the carry chain; prefetch depth 8.
// ---------------------------------------------------------------------------
__global__ __launch_bounds__(256) void pass2_kernel(
    const float* __restrict__ A_log, const float* __restrict__ E,
    const float* __restrict__ Dsum, float* __restrict__ Sin)
{
    const int g = blockIdx.x * 256 + threadIdx.x;     // 0..32767
    const int b = g >> 12;
    const int e = g & 4095;
    const int i = e >> 6;
    const float al = A_log[e] * 1.44269504f;

    float Eb[8], db[8];
    #pragma unroll
    for (int p = 0; p < 8; ++p) {
        size_t nb = (size_t)p * BATCH + b;
        Eb[p] = E[nb * 4096 + e];
        db[p] = EXP2(al * Dsum[nb * 64 + i]);
    }

    float carry = 0.f;
    #pragma unroll 8
    for (int c = 0; c < NC; ++c) {
        const int s = c & 7;
        float Ec = Eb[s], dc = db[s];
        if (c + 8 < NC) {
            size_t nb = (size_t)(c + 8) * BATCH + b;
            Eb[s] = E[nb * 4096 + e];
            db[s] = EXP2(al * Dsum[nb * 64 + i]);
        }
        Sin[((size_t)c * BATCH + b) * 4096 + e] = carry;
        carry = dc * carry + Ec;                      // the only serial dep
    }
}

// ---------------------------------------------------------------------------
// Kernel D (pass 3): replay chunk from true incoming state, emit
//   y[b,t,i] = sum_j Ct[b,t,j] * h[b,i,j]
// (i = tid>>2, jg = tid&3): 4 j-partials per i in adjacent lanes ->
// 2x shfl_xor, no in-loop barriers.
// ---------------------------------------------------------------------------
__global__ __launch_bounds__(256) void pass3_kernel(
    const float* __restrict__ delta_g, const float* __restrict__ u_g,
    const float* __restrict__ ct_g, const float* __restrict__ A_log,
    const float* __restrict__ Sin, float* __restrict__ out)
{
    __shared__ float s_d[CL * 64];
    __shared__ float s_u[CL * 64];
    __shared__ float s_c[CL * 64];

    const int c = blockIdx.x, b = blockIdx.y, tid = threadIdx.x;
    const int t0 = c * CL;

    const float4* dg = (const float4*)(delta_g + ((size_t)b * SEQ + t0) * DS);
    const float4* ug = (const float4*)(u_g     + ((size_t)b * SEQ + t0) * DS);
    const float4* cg = (const float4*)(ct_g    + ((size_t)b * SEQ + t0) * DS);
    #pragma unroll
    for (int it = 0; it < (CL * 64 / 4) / 256; ++it) {
        int f = tid + it * 256;
        ((float4*)s_d)[f] = dg[f];
        ((float4*)s_u)[f] = ug[f];
        ((float4*)s_c)[f] = cg[f];
    }

    const int i  = tid >> 2;                          // 0..63
    const int jg = tid & 3;                           // 0..3

    float alog[16];
    {
        const float4* ar = (const float4*)(A_log + i * 64 + jg * 16);
        #pragma unroll
        for (int qq = 0; qq < 4; ++qq) {
            float4 v = ar[qq];
            alog[4*qq+0] = v.x * 1.44269504f; alog[4*qq+1] = v.y * 1.44269504f;
            alog[4*qq+2] = v.z * 1.44269504f; alog[4*qq+3] = v.w * 1.44269504f;
        }
    }

    float h[16];
    {
        const float4* hin = (const float4*)(
            Sin + (((size_t)c * BATCH + b) * 64 + i) * 64 + jg * 16);
        #pragma unroll
        for (int qq = 0; qq < 4; ++qq) {
            float4 v = hin[qq];
            h[4*qq+0] = v.x; h[4*qq+1] = v.y; h[4*qq+2] = v.z; h[4*qq+3] = v.w;
        }
    }
    __syncthreads();

    for (int t = 0; t < CL; ++t) {
        float d = s_d[t * 64 + i];
        const float* up = s_u + t * 64 + jg * 16;
        const float* cp = s_c + t * 64 + jg * 16;
        float part = 0.f;
        #pragma unroll
        for (int k = 0; k < 16; ++k) {
            h[k] = EXP2(alog[k] * d) * h[k] + up[k];
            part += cp[k] * h[k];
        }
        part += __shfl_xor(part, 1);
        part += __shfl_xor(part, 2);
        if (jg == 0)
            out[((size_t)b * SEQ + t0 + t) * DS + i] = part;
    }
}

// ---------------------------------------------------------------------------
// Inputs: 0:x 1..6:(cog/beh/env dead) 7:W_delta 8:b_delta 9:W_Bp 10:b_Bp
//         11:W_Cp 12:b_Cp 13:A_log
// ---------------------------------------------------------------------------
extern "C" void kernel_launch(void* const* d_in, const int* in_sizes, int n_in,
                              void* d_out, int out_size, void* d_ws, size_t ws_size,
                              hipStream_t stream)
{
    const float* x     = (const float*)d_in[0];
    const float* Wd    = (const float*)d_in[7];
    const float* bd    = (const float*)d_in[8];
    const float* Wb    = (const float*)d_in[9];
    const float* bb    = (const float*)d_in[10];
    const float* Wc    = (const float*)d_in[11];
    const float* bc    = (const float*)d_in[12];
    const float* A_log = (const float*)d_in[13];
    float* out = (float*)d_out;

    float* ws = (float*)d_ws;
    float* delta_g = ws;                       // 1,048,576 floats
    float* u_g     = ws + 1 * 1048576;         // 1,048,576
    float* ct_g    = ws + 2 * 1048576;         // 1,048,576
    float* E       = ws + 3 * 1048576;         // 2,097,152
    float* Sin     = ws + 5 * 1048576;         // 2,097,152
    float* Dsum    = ws + 7 * 1048576;         // 32,768
    __bf16* Wp     = (__bf16*)E;               // aliases E (dead by pass1)

    wconv_kernel<<<768, 256, 0, stream>>>(Wd, Wb, Wc, Wp);
    proj_mfma<<<256, 256, 0, stream>>>(
        x, Wp, bd, bb, bc, delta_g, u_g, ct_g);
    pass1_kernel<<<dim3(NC, BATCH), 256, 0, stream>>>(
        delta_g, u_g, A_log, E, Dsum);
    pass2_kernel<<<128, 256, 0, stream>>>(
        A_log, E, Dsum, Sin);
    pass3_kernel<<<dim3(NC, BATCH), 256, 0, stream>>>(
        delta_g, u_g, ct_g, A_log, Sin, out);
}

// Round 7
// 186.891 us; speedup vs baseline: 1.1733x; 1.0674x over previous
//
#include <hip/hip_runtime.h>
#include <math.h>

#define DM   1024
#define DS   64
#define BATCH 8
#define SEQ  2048
#define CL   32          // chunk length
#define NC   64          // number of chunks (SEQ/CL)

typedef __bf16 bf16x8 __attribute__((ext_vector_type(8)));
typedef float  f32x4  __attribute__((ext_vector_type(4)));

#if __has_builtin(__builtin_amdgcn_exp2f)
#define EXP2(v) __builtin_amdgcn_exp2f(v)
#else
#define EXP2(v) __expf(0.69314718056f * (v))
#endif

// ---------------------------------------------------------------------------
// Kernel W: pre-convert W_delta|W_Bp|W_Cp into packed bf16, K-tiled:
// Wp[(kt*192 + n)*32 + kk], k = kt*32+kk (kt = 32-wide K slab).
// A 64-K block kb is the contiguous 24 KB at Wp + kb*12288 elements.
// ---------------------------------------------------------------------------
__global__ __launch_bounds__(256) void wconv_kernel(
    const float* __restrict__ Wd, const float* __restrict__ Wb,
    const float* __restrict__ Wc, __bf16* __restrict__ Wp)
{
    int idx = blockIdx.x * 256 + threadIdx.x;   // n*1024 + k
    int k  = idx & 1023;
    int n  = idx >> 10;                          // 0..191
    const float* W = (n < 64) ? Wd : (n < 128 ? Wb : Wc);
    float v = W[(size_t)(n & 63) * DM + k];
    int kt = k >> 5, kk = k & 31;
    Wp[((size_t)kt * 192 + n) * 32 + kk] = (__bf16)v;
}

// ---------------------------------------------------------------------------
// Kernel A: MFMA projection, v7 — occupancy-first.
// r6 failure: grid 256 = 1 block/CU = 1 wave/SIMD -> every vmcnt wait was
// pure SIMD idle (Occupancy 8.2%, MfmaUtil 4.7%).  v7: tile 32M x 192N,
// grid 512 = 2 blocks/CU (independent barriers -> one block computes while
// the other drains staging), 8 waves/CU.
// Wave = 32M x 48N as 2x3 16-wide tiles (16x16x32 MFMA, acc 24 VGPR).
// BK=64, double-buffered LDS, ONE barrier/iter (16 total).
// B staging: LDS layout == Wp layout, so chunk g (16B) goes
//   sB[bi] + g*8 shorts  <-  Wp + kb*12288 + g*8   (trivially correct).
// A staging: f32->bf16 into stride-72 rows (all LDS access patterns audited
// uniform 8-phase).  MFMA layouts (m89/m91): A/B[k=quad*8+j][m|n=l15],
// D: col=l15, row=quad*4+reg.
// ---------------------------------------------------------------------------
__global__ __launch_bounds__(256, 2) void proj_mfma(
    const float* __restrict__ x, const __bf16* __restrict__ Wp,
    const float* __restrict__ bd, const float* __restrict__ bb,
    const float* __restrict__ bc,
    float* __restrict__ delta_g, float* __restrict__ u_g,
    float* __restrict__ ct_g)
{
    __shared__ __bf16 sB[2][12288];              // 2 x 24 KB (2 32-K slabs)
    __shared__ __bf16 sA[2][32 * 72];            // 2 x 4.5 KB, padded rows

    const int tid  = threadIdx.x;
    const int row0 = blockIdx.x * 32;

    const int lane = tid & 63, wv = tid >> 6;
    const int l15  = lane & 15, quad = lane >> 4;
    const int nbase = wv * 48;                   // wave's N window

    const int am = tid >> 3;                     // staging row 0..31
    const int ak = tid & 7;                      // 8-float k-group 0..7
    const float* xga = x + (size_t)(row0 + am) * DM + ak * 8;

    f32x4 acc[2][3];
    #pragma unroll
    for (int mt = 0; mt < 2; ++mt)
        #pragma unroll
        for (int nt = 0; nt < 3; ++nt)
            acc[mt][nt] = (f32x4){0.f, 0.f, 0.f, 0.f};

    uint4  wreg[6];
    float4 areg[2];

    #define LOADB(kb) do {                                                    \
        _Pragma("unroll")                                                     \
        for (int it = 0; it < 6; ++it)                                        \
            wreg[it] = *(const uint4*)(                                       \
                Wp + (size_t)(kb) * 12288 + (tid + it * 256) * 8);            \
    } while (0)
    #define LOADA(kb) do {                                                    \
        areg[0] = *(const float4*)(xga + (kb) * 64);                          \
        areg[1] = *(const float4*)(xga + (kb) * 64 + 4);                      \
    } while (0)
    #define STAGE(bi) do {                                                    \
        _Pragma("unroll")                                                     \
        for (int it = 0; it < 6; ++it)                                        \
            *(uint4*)&sB[bi][(tid + it * 256) * 8] = wreg[it];                \
        bf16x8 hv = {(__bf16)areg[0].x, (__bf16)areg[0].y,                    \
                     (__bf16)areg[0].z, (__bf16)areg[0].w,                    \
                     (__bf16)areg[1].x, (__bf16)areg[1].y,                    \
                     (__bf16)areg[1].z, (__bf16)areg[1].w};                   \
        *(bf16x8*)&sA[bi][am * 72 + ak * 8] = hv;                             \
    } while (0)
    #define COMPUTE(bi) do {                                                  \
        _Pragma("unroll")                                                     \
        for (int s = 0; s < 2; ++s) {                                         \
            bf16x8 af[2];                                                     \
            _Pragma("unroll")                                                 \
            for (int mt = 0; mt < 2; ++mt)                                    \
                af[mt] = *(const bf16x8*)                                     \
                    &sA[bi][(mt * 16 + l15) * 72 + s * 32 + quad * 8];        \
            _Pragma("unroll")                                                 \
            for (int nt = 0; nt < 3; ++nt) {                                  \
                bf16x8 bv = *(const bf16x8*)                                  \
                    &sB[bi][s * 6144 + (nbase + nt * 16 + l15) * 32           \
                            + quad * 8];                                      \
                _Pragma("unroll")                                             \
                for (int mt = 0; mt < 2; ++mt)                                \
                    acc[mt][nt] = __builtin_amdgcn_mfma_f32_16x16x32_bf16(    \
                        af[mt], bv, acc[mt][nt], 0, 0, 0);                    \
            }                                                                 \
        }                                                                     \
    } while (0)

    LOADB(0);
    LOADA(0);
    STAGE(0);
    __syncthreads();

    int buf = 0;
    for (int kb = 0; kb < 16; ++kb) {
        if (kb < 15) {
            LOADB(kb + 1);                       // issue globals early
            LOADA(kb + 1);
        }
        COMPUTE(buf);
        if (kb < 15) STAGE(buf ^ 1);             // other buffer
        __syncthreads();                         // one barrier per iter
        buf ^= 1;
    }
    #undef LOADB
    #undef LOADA
    #undef STAGE
    #undef COMPUTE

    // epilogue: bias + activations + stores (D: col=l15, row=quad*4+r)
    #pragma unroll
    for (int nt = 0; nt < 3; ++nt) {
        int gn  = nbase + nt * 16 + l15;         // 0..191
        int mat = (nbase + nt * 16) >> 6;        // wave-uniform per nt
        int col = gn & 63;
        float bias = (mat == 0) ? bd[col] : (mat == 1 ? bb[col] : bc[col]);
        #pragma unroll
        for (int mt = 0; mt < 2; ++mt) {
            #pragma unroll
            for (int r = 0; r < 4; ++r) {
                int m = row0 + mt * 16 + quad * 4 + r;
                float v = acc[mt][nt][r] + bias;
                if (mat == 0) {
                    float sp = (v > 20.f) ? v : __logf(1.f + __expf(v));
                    delta_g[(size_t)m * DS + col] = sp;
                } else if (mat == 1) {
                    u_g[(size_t)m * DS + col] = v * x[(size_t)m * DM + col];
                } else {
                    ct_g[(size_t)m * DS + col] = v;
                }
            }
        }
    }
}

// ---------------------------------------------------------------------------
// Kernel B (pass 1): per-chunk local recurrence from h=0. (unchanged r6)
// ---------------------------------------------------------------------------
__global__ __launch_bounds__(256) void pass1_kernel(
    const float* __restrict__ delta_g, const float* __restrict__ u_g,
    const float* __restrict__ A_log,
    float* __restrict__ E, float* __restrict__ Dsum)
{
    __shared__ float s_d[CL * 64];
    __shared__ float s_u[CL * 64];
    const int c = blockIdx.x, b = blockIdx.y, tid = threadIdx.x;
    const int t0 = c * CL;

    const float4* dg = (const float4*)(delta_g + ((size_t)b * SEQ + t0) * DS);
    const float4* ug = (const float4*)(u_g     + ((size_t)b * SEQ + t0) * DS);
    #pragma unroll
    for (int it = 0; it < (CL * 64 / 4) / 256; ++it) {
        int f = tid + it * 256;
        ((float4*)s_d)[f] = dg[f];
        ((float4*)s_u)[f] = ug[f];
    }

    const int i  = tid & 63;
    const int jg = tid >> 6;
    float alog[16];
    {
        const float4* ar = (const float4*)(A_log + i * 64 + jg * 16);
        #pragma unroll
        for (int qq = 0; qq < 4; ++qq) {
            float4 v = ar[qq];
            alog[4*qq+0] = v.x * 1.44269504f; alog[4*qq+1] = v.y * 1.44269504f;
            alog[4*qq+2] = v.z * 1.44269504f; alog[4*qq+3] = v.w * 1.44269504f;
        }
    }
    __syncthreads();

    float h[16];
    #pragma unroll
    for (int k = 0; k < 16; ++k) h[k] = 0.f;
    float dsum = 0.f;

    for (int t = 0; t < CL; ++t) {
        float d = s_d[t * 64 + i];
        dsum += d;
        const float* up = s_u + t * 64 + jg * 16;
        #pragma unroll
        for (int k = 0; k < 16; ++k)
            h[k] = EXP2(alog[k] * d) * h[k] + up[k];
    }

    float* eo = E + (((size_t)c * BATCH + b) * 64 + i) * 64 + jg * 16;
    #pragma unroll
    for (int qq = 0; qq < 4; ++qq)
        ((float4*)eo)[qq] = make_float4(h[4*qq], h[4*qq+1], h[4*qq+2], h[4*qq+3]);
    if (jg == 0) Dsum[((size_t)c * BATCH + b) * 64 + i] = dsum;
}

// ---------------------------------------------------------------------------
// Kernel C (pass 2): sequential chunk scan, parallel over B*64*64 elements.
// (unchanged r6)
// ---------------------------------------------------------------------------
__global__ __launch_bounds__(256) void pass2_kernel(
    const float* __restrict__ A_log, const float* __restrict__ E,
    const float* __restrict__ Dsum, float* __restrict__ Sin)
{
    const int g = blockIdx.x * 256 + threadIdx.x;     // 0..32767
    const int b = g >> 12;
    const int e = g & 4095;
    const int i = e >> 6;
    const float al = A_log[e] * 1.44269504f;

    float Eb[8], db[8];
    #pragma unroll
    for (int p = 0; p < 8; ++p) {
        size_t nb = (size_t)p * BATCH + b;
        Eb[p] = E[nb * 4096 + e];
        db[p] = EXP2(al * Dsum[nb * 64 + i]);
    }

    float carry = 0.f;
    #pragma unroll 8
    for (int c = 0; c < NC; ++c) {
        const int s = c & 7;
        float Ec = Eb[s], dc = db[s];
        if (c + 8 < NC) {
            size_t nb = (size_t)(c + 8) * BATCH + b;
            Eb[s] = E[nb * 4096 + e];
            db[s] = EXP2(al * Dsum[nb * 64 + i]);
        }
        Sin[((size_t)c * BATCH + b) * 4096 + e] = carry;
        carry = dc * carry + Ec;                      // the only serial dep
    }
}

// ---------------------------------------------------------------------------
// Kernel D (pass 3): replay chunk from true incoming state, emit
//   y[b,t,i] = sum_j Ct[b,t,j] * h[b,i,j]   (unchanged r6)
// ---------------------------------------------------------------------------
__global__ __launch_bounds__(256) void pass3_kernel(
    const float* __restrict__ delta_g, const float* __restrict__ u_g,
    const float* __restrict__ ct_g, const float* __restrict__ A_log,
    const float* __restrict__ Sin, float* __restrict__ out)
{
    __shared__ float s_d[CL * 64];
    __shared__ float s_u[CL * 64];
    __shared__ float s_c[CL * 64];

    const int c = blockIdx.x, b = blockIdx.y, tid = threadIdx.x;
    const int t0 = c * CL;

    const float4* dg = (const float4*)(delta_g + ((size_t)b * SEQ + t0) * DS);
    const float4* ug = (const float4*)(u_g     + ((size_t)b * SEQ + t0) * DS);
    const float4* cg = (const float4*)(ct_g    + ((size_t)b * SEQ + t0) * DS);
    #pragma unroll
    for (int it = 0; it < (CL * 64 / 4) / 256; ++it) {
        int f = tid + it * 256;
        ((float4*)s_d)[f] = dg[f];
        ((float4*)s_u)[f] = ug[f];
        ((float4*)s_c)[f] = cg[f];
    }

    const int i  = tid >> 2;                          // 0..63
    const int jg = tid & 3;                           // 0..3

    float alog[16];
    {
        const float4* ar = (const float4*)(A_log + i * 64 + jg * 16);
        #pragma unroll
        for (int qq = 0; qq < 4; ++qq) {
            float4 v = ar[qq];
            alog[4*qq+0] = v.x * 1.44269504f; alog[4*qq+1] = v.y * 1.44269504f;
            alog[4*qq+2] = v.z * 1.44269504f; alog[4*qq+3] = v.w * 1.44269504f;
        }
    }

    float h[16];
    {
        const float4* hin = (const float4*)(
            Sin + (((size_t)c * BATCH + b) * 64 + i) * 64 + jg * 16);
        #pragma unroll
        for (int qq = 0; qq < 4; ++qq) {
            float4 v = hin[qq];
            h[4*qq+0] = v.x; h[4*qq+1] = v.y; h[4*qq+2] = v.z; h[4*qq+3] = v.w;
        }
    }
    __syncthreads();

    for (int t = 0; t < CL; ++t) {
        float d = s_d[t * 64 + i];
        const float* up = s_u + t * 64 + jg * 16;
        const float* cp = s_c + t * 64 + jg * 16;
        float part = 0.f;
        #pragma unroll
        for (int k = 0; k < 16; ++k) {
            h[k] = EXP2(alog[k] * d) * h[k] + up[k];
            part += cp[k] * h[k];
        }
        part += __shfl_xor(part, 1);
        part += __shfl_xor(part, 2);
        if (jg == 0)
            out[((size_t)b * SEQ + t0 + t) * DS + i] = part;
    }
}

// ---------------------------------------------------------------------------
// Inputs: 0:x 1..6:(cog/beh/env dead) 7:W_delta 8:b_delta 9:W_Bp 10:b_Bp
//         11:W_Cp 12:b_Cp 13:A_log
// ---------------------------------------------------------------------------
extern "C" void kernel_launch(void* const* d_in, const int* in_sizes, int n_in,
                              void* d_out, int out_size, void* d_ws, size_t ws_size,
                              hipStream_t stream)
{
    const float* x     = (const float*)d_in[0];
    const float* Wd    = (const float*)d_in[7];
    const float* bd    = (const float*)d_in[8];
    const float* Wb    = (const float*)d_in[9];
    const float* bb    = (const float*)d_in[10];
    const float* Wc    = (const float*)d_in[11];
    const float* bc    = (const float*)d_in[12];
    const float* A_log = (const float*)d_in[13];
    float* out = (float*)d_out;

    float* ws = (float*)d_ws;
    float* delta_g = ws;                       // 1,048,576 floats
    float* u_g     = ws + 1 * 1048576;         // 1,048,576
    float* ct_g    = ws + 2 * 1048576;         // 1,048,576
    float* E       = ws + 3 * 1048576;         // 2,097,152
    float* Sin     = ws + 5 * 1048576;         // 2,097,152
    float* Dsum    = ws + 7 * 1048576;         // 32,768
    __bf16* Wp     = (__bf16*)E;               // aliases E (dead by pass1)

    wconv_kernel<<<768, 256, 0, stream>>>(Wd, Wb, Wc, Wp);
    proj_mfma<<<512, 256, 0, stream>>>(
        x, Wp, bd, bb, bc, delta_g, u_g, ct_g);
    pass1_kernel<<<dim3(NC, BATCH), 256, 0, stream>>>(
        delta_g, u_g, A_log, E, Dsum);
    pass2_kernel<<<128, 256, 0, stream>>>(
        A_log, E, Dsum, Sin);
    pass3_kernel<<<dim3(NC, BATCH), 256, 0, stream>>>(
        delta_g, u_g, ct_g, A_log, Sin, out);
}

// Round 9
// 186.045 us; speedup vs baseline: 1.1787x; 1.0045x over previous
//
#include <hip/hip_runtime.h>
#include <math.h>

#define DM   1024
#define DS   64
#define BATCH 8
#define SEQ  2048
#define CL   32          // chunk length
#define NC   64          // number of chunks (SEQ/CL)

typedef __bf16 bf16x8 __attribute__((ext_vector_type(8)));
typedef float  f32x4  __attribute__((ext_vector_type(4)));

#if __has_builtin(__builtin_amdgcn_exp2f)
#define EXP2(v) __builtin_amdgcn_exp2f(v)
#else
#define EXP2(v) __expf(0.69314718056f * (v))
#endif

// ---------------------------------------------------------------------------
// Kernel W: pre-convert W_delta|W_Bp|W_Cp into packed bf16, K-tiled:
// Wp[(kt*192 + n)*32 + kk], k = kt*32+kk.  A 64-K block kb = contiguous
// 24 KB at Wp + kb*12288 elements.
// ---------------------------------------------------------------------------
__global__ __launch_bounds__(256) void wconv_kernel(
    const float* __restrict__ Wd, const float* __restrict__ Wb,
    const float* __restrict__ Wc, __bf16* __restrict__ Wp)
{
    int idx = blockIdx.x * 256 + threadIdx.x;   // n*1024 + k
    int k  = idx & 1023;
    int n  = idx >> 10;                          // 0..191
    const float* W = (n < 64) ? Wd : (n < 128 ? Wb : Wc);
    float v = W[(size_t)(n & 63) * DM + k];
    int kt = k >> 5, kk = k & 31;
    Wp[((size_t)kt * 192 + n) * 32 + kk] = (__bf16)v;
}

// ---------------------------------------------------------------------------
// Kernel A+B fused: projection (v7 core) + pass1 local scan.
// A proj block (32 consecutive rows of one batch) IS one (b,c) chunk: after
// the GEMM epilogue, softplus(delta) and u drop into LDS, one barrier, and
// the per-chunk recurrence runs in the same kernel (saves a launch and an
// 8 MB re-read).  B staging via __builtin_amdgcn_global_load_lds width=16
// (pattern is exactly wave-uniform-base + lane*16B).  One barrier per
// K-iter.  Grid 512 = 2 blocks/CU (independent barriers overlap).
// LDS: 48K (sB dbuf) + 9K (sA dbuf) + 16K (s_d,s_u) = 73.7 KB -> 2 blk/CU.
// MFMA layouts (m89/m91): A/B frag [k=quad*8+j][m|n=l15]; D: col=l15,
// row=quad*4+reg.
// ---------------------------------------------------------------------------
__global__ __launch_bounds__(256, 2) void projp1_full(
    const float* __restrict__ x, const __bf16* __restrict__ Wp,
    const float* __restrict__ bd, const float* __restrict__ bb,
    const float* __restrict__ bc, const float* __restrict__ A_log,
    float* __restrict__ delta_g, float* __restrict__ u_g,
    float* __restrict__ ct_g,
    float* __restrict__ E, float* __restrict__ Dsum)
{
    __shared__ __bf16 sB[2][12288];              // 2 x 24 KB
    __shared__ __bf16 sA[2][32 * 72];            // 2 x 4.5 KB
    __shared__ float  s_d[CL * 64];              // 8 KB
    __shared__ float  s_u[CL * 64];              // 8 KB

    const int tid  = threadIdx.x;
    const int row0 = blockIdx.x * 32;

    const int lane = tid & 63, wv = tid >> 6;
    const int l15  = lane & 15, quad = lane >> 4;
    const int nbase = wv * 48;                   // wave's N window

    const int am = tid >> 3;                     // staging row 0..31
    const int ak = tid & 7;                      // 8-float k-group 0..7
    const float* xga = x + (size_t)(row0 + am) * DM + ak * 8;

    f32x4 acc[2][3];
    #pragma unroll
    for (int mt = 0; mt < 2; ++mt)
        #pragma unroll
        for (int nt = 0; nt < 3; ++nt)
            acc[mt][nt] = (f32x4){0.f, 0.f, 0.f, 0.f};

    float4 areg[2];

#if __has_builtin(__builtin_amdgcn_global_load_lds)
    #define LOADB(kb, bi) do {                                                \
        _Pragma("unroll")                                                     \
        for (int it = 0; it < 6; ++it) {                                      \
            const __bf16* gsrc =                                              \
                Wp + (size_t)(kb) * 12288 + (tid + it * 256) * 8;             \
            __bf16* ldst = &sB[bi][(tid + it * 256) * 8];                     \
            __builtin_amdgcn_global_load_lds(                                 \
                (const __attribute__((address_space(1))) void*)gsrc,          \
                (__attribute__((address_space(3))) void*)ldst, 16, 0, 0);     \
        }                                                                     \
    } while (0)
#else
    #define LOADB(kb, bi) do {                                                \
        _Pragma("unroll")                                                     \
        for (int it = 0; it < 6; ++it) {                                      \
            uint4 t = *(const uint4*)(                                        \
                Wp + (size_t)(kb) * 12288 + (tid + it * 256) * 8);            \
            *(uint4*)&sB[bi][(tid + it * 256) * 8] = t;                       \
        }                                                                     \
    } while (0)
#endif
    #define LOADA(kb) do {                                                    \
        areg[0] = *(const float4*)(xga + (kb) * 64);                          \
        areg[1] = *(const float4*)(xga + (kb) * 64 + 4);                      \
    } while (0)
    #define STAGEA(bi) do {                                                   \
        bf16x8 hv = {(__bf16)areg[0].x, (__bf16)areg[0].y,                    \
                     (__bf16)areg[0].z, (__bf16)areg[0].w,                    \
                     (__bf16)areg[1].x, (__bf16)areg[1].y,                    \
                     (__bf16)areg[1].z, (__bf16)areg[1].w};                   \
        *(bf16x8*)&sA[bi][am * 72 + ak * 8] = hv;                             \
    } while (0)
    #define COMPUTE(bi) do {                                                  \
        _Pragma("unroll")                                                     \
        for (int s = 0; s < 2; ++s) {                                         \
            bf16x8 af[2];                                                     \
            _Pragma("unroll")                                                 \
            for (int mt = 0; mt < 2; ++mt)                                    \
                af[mt] = *(const bf16x8*)                                     \
                    &sA[bi][(mt * 16 + l15) * 72 + s * 32 + quad * 8];        \
            _Pragma("unroll")                                                 \
            for (int nt = 0; nt < 3; ++nt) {                                  \
                bf16x8 bv = *(const bf16x8*)                                  \
                    &sB[bi][s * 6144 + (nbase + nt * 16 + l15) * 32           \
                            + quad * 8];                                      \
                _Pragma("unroll")                                             \
                for (int mt = 0; mt < 2; ++mt)                                \
                    acc[mt][nt] = __builtin_amdgcn_mfma_f32_16x16x32_bf16(    \
                        af[mt], bv, acc[mt][nt], 0, 0, 0);                    \
            }                                                                 \
        }                                                                     \
    } while (0)

    LOADB(0, 0);
    LOADA(0);
    STAGEA(0);
    __syncthreads();                             // drains vmcnt before use

    int buf = 0;
    for (int kb = 0; kb < 16; ++kb) {
        if (kb < 15) {
            LOADB(kb + 1, buf ^ 1);              // async global->LDS
            LOADA(kb + 1);
        }
        COMPUTE(buf);
        if (kb < 15) STAGEA(buf ^ 1);
        __syncthreads();                         // one barrier per iter
        buf ^= 1;
    }
    #undef LOADB
    #undef LOADA
    #undef STAGEA
    #undef COMPUTE

    // epilogue: bias + activations; store global AND stage delta/u in LDS
    #pragma unroll
    for (int nt = 0; nt < 3; ++nt) {
        int gn  = nbase + nt * 16 + l15;         // 0..191
        int mat = (nbase + nt * 16) >> 6;        // wave-uniform per nt
        int col = gn & 63;
        float bias = (mat == 0) ? bd[col] : (mat == 1 ? bb[col] : bc[col]);
        #pragma unroll
        for (int mt = 0; mt < 2; ++mt) {
            #pragma unroll
            for (int r = 0; r < 4; ++r) {
                int tl = mt * 16 + quad * 4 + r; // local t 0..31
                int m  = row0 + tl;
                float v = acc[mt][nt][r] + bias;
                if (mat == 0) {
                    float sp = (v > 20.f) ? v : __logf(1.f + __expf(v));
                    delta_g[(size_t)m * DS + col] = sp;
                    s_d[tl * 64 + col] = sp;
                } else if (mat == 1) {
                    float uu = v * x[(size_t)m * DM + col];
                    u_g[(size_t)m * DS + col] = uu;
                    s_u[tl * 64 + col] = uu;
                } else {
                    ct_g[(size_t)m * DS + col] = v;
                }
            }
        }
    }
    __syncthreads();

    // ---- fused pass1: local chunk scan from h=0 ----
    const int bidx = row0 >> 11;                 // batch  (row0/2048)
    const int cidx = (row0 >> 5) & 63;           // chunk  ((row0/32)%64)
    const int si = tid & 63;
    const int sj = tid >> 6;

    float alog[16];
    {
        const float4* ar = (const float4*)(A_log + si * 64 + sj * 16);
        #pragma unroll
        for (int qq = 0; qq < 4; ++qq) {
            float4 v = ar[qq];
            alog[4*qq+0] = v.x * 1.44269504f; alog[4*qq+1] = v.y * 1.44269504f;
            alog[4*qq+2] = v.z * 1.44269504f; alog[4*qq+3] = v.w * 1.44269504f;
        }
    }

    float h[16];
    #pragma unroll
    for (int k = 0; k < 16; ++k) h[k] = 0.f;
    float dsum = 0.f;

    for (int t = 0; t < CL; ++t) {
        float d = s_d[t * 64 + si];
        dsum += d;
        const float* up = s_u + t * 64 + sj * 16;
        #pragma unroll
        for (int k = 0; k < 16; ++k)
            h[k] = EXP2(alog[k] * d) * h[k] + up[k];
    }

    float* eo = E + (((size_t)cidx * BATCH + bidx) * 64 + si) * 64 + sj * 16;
    #pragma unroll
    for (int qq = 0; qq < 4; ++qq)
        ((float4*)eo)[qq] = make_float4(h[4*qq], h[4*qq+1], h[4*qq+2], h[4*qq+3]);
    if (sj == 0) Dsum[((size_t)cidx * BATCH + bidx) * 64 + si] = dsum;
}

// ---------------------------------------------------------------------------
// Kernel C+D fused: each block (c,b) computes its OWN incoming state by
// scanning E/Dsum of chunks < c (replaces pass2 + the Sin round trip),
// then replays the chunk and emits y.  (i = tid>>2, jg = tid&3): 4
// j-partials per i in adjacent lanes -> 2x shfl_xor, no in-loop barriers.
// ---------------------------------------------------------------------------
__global__ __launch_bounds__(256) void pass23_kernel(
    const float* __restrict__ delta_g, const float* __restrict__ u_g,
    const float* __restrict__ ct_g, const float* __restrict__ A_log,
    const float* __restrict__ E, const float* __restrict__ Dsum,
    float* __restrict__ out)
{
    __shared__ float s_d[CL * 64];
    __shared__ float s_u[CL * 64];
    __shared__ float s_c[CL * 64];

    const int c = blockIdx.x, b = blockIdx.y, tid = threadIdx.x;
    const int t0 = c * CL;

    const float4* dg = (const float4*)(delta_g + ((size_t)b * SEQ + t0) * DS);
    const float4* ug = (const float4*)(u_g     + ((size_t)b * SEQ + t0) * DS);
    const float4* cg = (const float4*)(ct_g    + ((size_t)b * SEQ + t0) * DS);
    #pragma unroll
    for (int it = 0; it < (CL * 64 / 4) / 256; ++it) {
        int f = tid + it * 256;
        ((float4*)s_d)[f] = dg[f];
        ((float4*)s_u)[f] = ug[f];
        ((float4*)s_c)[f] = cg[f];
    }

    const int i  = tid >> 2;                          // 0..63
    const int jg = tid & 3;                           // 0..3

    float alog[16];
    {
        const float4* ar = (const float4*)(A_log + i * 64 + jg * 16);
        #pragma unroll
        for (int qq = 0; qq < 4; ++qq) {
            float4 v = ar[qq];
            alog[4*qq+0] = v.x * 1.44269504f; alog[4*qq+1] = v.y * 1.44269504f;
            alog[4*qq+2] = v.z * 1.44269504f; alog[4*qq+3] = v.w * 1.44269504f;
        }
    }

    // ---- fused pass2: compute incoming state for this chunk ----
    float h[16];
    #pragma unroll
    for (int k = 0; k < 16; ++k) h[k] = 0.f;

    for (int cp = 0; cp < c; ++cp) {
        float ds = Dsum[((size_t)cp * BATCH + b) * 64 + i];
        const float4* ep = (const float4*)(
            E + (((size_t)cp * BATCH + b) * 64 + i) * 64 + jg * 16);
        float4 e0 = ep[0], e1 = ep[1], e2 = ep[2], e3 = ep[3];
        float ev[16] = {e0.x,e0.y,e0.z,e0.w, e1.x,e1.y,e1.z,e1.w,
                        e2.x,e2.y,e2.z,e2.w, e3.x,e3.y,e3.z,e3.w};
        #pragma unroll
        for (int k = 0; k < 16; ++k)
            h[k] = EXP2(alog[k] * ds) * h[k] + ev[k];
    }
    __syncthreads();

    // ---- replay + output ----
    for (int t = 0; t < CL; ++t) {
        float d = s_d[t * 64 + i];
        const float* up  = s_u + t * 64 + jg * 16;
        const float* cp2 = s_c + t * 64 + jg * 16;
        float part = 0.f;
        #pragma unroll
        for (int k = 0; k < 16; ++k) {
            h[k] = EXP2(alog[k] * d) * h[k] + up[k];
            part += cp2[k] * h[k];
        }
        part += __shfl_xor(part, 1);
        part += __shfl_xor(part, 2);
        if (jg == 0)
            out[((size_t)b * SEQ + t0 + t) * DS + i] = part;
    }
}

// ---------------------------------------------------------------------------
// Inputs: 0:x 1..6:(cog/beh/env dead) 7:W_delta 8:b_delta 9:W_Bp 10:b_Bp
//         11:W_Cp 12:b_Cp 13:A_log
// ---------------------------------------------------------------------------
extern "C" void kernel_launch(void* const* d_in, const int* in_sizes, int n_in,
                              void* d_out, int out_size, void* d_ws, size_t ws_size,
                              hipStream_t stream)
{
    const float* x     = (const float*)d_in[0];
    const float* Wd    = (const float*)d_in[7];
    const float* bd    = (const float*)d_in[8];
    const float* Wb    = (const float*)d_in[9];
    const float* bb    = (const float*)d_in[10];
    const float* Wc    = (const float*)d_in[11];
    const float* bc    = (const float*)d_in[12];
    const float* A_log = (const float*)d_in[13];
    float* out = (float*)d_out;

    float* ws = (float*)d_ws;
    float* delta_g = ws;                       // 1,048,576 floats
    float* u_g     = ws + 1 * 1048576;         // 1,048,576
    float* ct_g    = ws + 2 * 1048576;         // 1,048,576
    float* E       = ws + 3 * 1048576;         // 2,097,152
    float* Dsum    = ws + 5 * 1048576;         // 32,768
    __bf16* Wp     = (__bf16*)(ws + 5 * 1048576 + 65536);  // own region

    wconv_kernel<<<768, 256, 0, stream>>>(Wd, Wb, Wc, Wp);
    projp1_full<<<512, 256, 0, stream>>>(
        x, Wp, bd, bb, bc, A_log, delta_g, u_g, ct_g, E, Dsum);
    pass23_kernel<<<dim3(NC, BATCH), 256, 0, stream>>>(
        delta_g, u_g, ct_g, A_log, E, Dsum, out);
}